// Round 4
// baseline (359.295 us; speedup 1.0000x reference)
//
#include <hip/hip_runtime.h>
#include <math.h>

#define NEG_BIG (-1e30f)

typedef __attribute__((ext_vector_type(8))) short short8;
typedef __attribute__((ext_vector_type(4))) float floatx4;

__device__ __forceinline__ unsigned short f2bf(float x) {
    unsigned u = __float_as_uint(x);
    unsigned r = (u + 0x7fffu + ((u >> 16) & 1u)) >> 16;
    return (unsigned short)r;
}
__device__ __forceinline__ float bf2f(unsigned short h) {
    return __uint_as_float(((unsigned)h) << 16);
}

// ---------------- prep: split W_atom (512x512, [k][n]) into 3 bf16 planes laid out [n][k] ----------------
__global__ void k_prepWa(const float* __restrict__ W, short* __restrict__ H,
                         short* __restrict__ M, short* __restrict__ L) {
    int t = blockIdx.x * 256 + threadIdx.x;   // 262144
    int n = t >> 9, k = t & 511;
    float x = W[(size_t)k * 512 + n];
    unsigned short h0 = f2bf(x); float r1 = x - bf2f(h0);
    unsigned short h1 = f2bf(r1); float r2 = r1 - bf2f(h1);
    unsigned short h2 = f2bf(r2);
    H[t] = (short)h0; M[t] = (short)h1; L[t] = (short)h2;
}

// ---------------- prep: W_bond (512x16 -> [h][k] bf16) ----------------
__global__ void k_prepWb(const float* __restrict__ Wb, short* __restrict__ Wbt) {
    int t = blockIdx.x * 256 + threadIdx.x;   // 8192
    int h = t >> 9, k = t & 511;
    Wbt[t] = (short)f2bf(Wb[(size_t)k * 16 + h]);
}

// ---------------- atoms GEMM via MFMA, fp32 emulated with 3-way bf16 split (6 products) ----------------
// tile 128x128, BK=32; one block = one molecule (blockIdx.y), 4 n-tiles (blockIdx.x)
// A staged through LDS (needs f32->bf16 split); B fragments loaded DIRECTLY from
// global planes (already [n][k] = MFMA fragment order; 1.5 MB unique -> L2-hot).
__global__ __launch_bounds__(256) void k_atoms_mfma(
    const float* __restrict__ fA, const float* __restrict__ fAo,
    const int* __restrict__ a_scope,
    const short* __restrict__ WH, const short* __restrict__ WM, const short* __restrict__ WL,
    const float* __restrict__ bias, float* __restrict__ out, int Bmol)
{
    __shared__ short A_s[3][128 * 40];   // [split][m][k] pad 40
    __shared__ int rs[128];

    const int tid = threadIdx.x;
    const int n0 = blockIdx.x * 128;
    const int mol = blockIdx.y;

    if (tid < 128) {
        int len = a_scope[2 * mol + 1];
        rs[tid] = (tid < len) ? (a_scope[2 * mol] + tid) : -1;
    }
    const int wid = tid >> 6, lane = tid & 63;
    const int wm = (wid >> 1) * 64, wn = (wid & 1) * 64;
    const int quad = lane >> 4, l16 = lane & 15;

    floatx4 acc[4][4];
#pragma unroll
    for (int i = 0; i < 4; i++)
#pragma unroll
        for (int j = 0; j < 4; j++) acc[i][j] = (floatx4){0.f, 0.f, 0.f, 0.f};

    const int ar = tid >> 1;           // 0..127 : A row in tile
    const int ak = (tid & 1) * 16;     // 0 / 16 : k segment
    __syncthreads();                   // rs ready
    const int asrc = rs[ar];

    for (int k0 = 0; k0 < 512; k0 += 32) {
        // ---- A global load + 3-way bf16 split ----
        float x[16];
        if (asrc >= 0) {
            int kg = k0 + ak;
            const float* p = (kg < 256) ? (fA + (size_t)asrc * 256 + kg)
                                        : (fAo + (size_t)asrc * 256 + (kg - 256));
#pragma unroll
            for (int i = 0; i < 4; i++) {
                float4 v = ((const float4*)p)[i];
                x[i * 4 + 0] = v.x; x[i * 4 + 1] = v.y;
                x[i * 4 + 2] = v.z; x[i * 4 + 3] = v.w;
            }
        } else {
#pragma unroll
            for (int i = 0; i < 16; i++) x[i] = 0.f;
        }
        short8 a00, a01, a10, a11, a20, a21;
#pragma unroll
        for (int i = 0; i < 8; i++) {
            unsigned short h0 = f2bf(x[i]); float r1 = x[i] - bf2f(h0);
            unsigned short h1 = f2bf(r1);   float r2 = r1 - bf2f(h1);
            a00[i] = (short)h0; a10[i] = (short)h1; a20[i] = (short)f2bf(r2);
        }
#pragma unroll
        for (int i = 0; i < 8; i++) {
            float xx = x[8 + i];
            unsigned short h0 = f2bf(xx); float r1 = xx - bf2f(h0);
            unsigned short h1 = f2bf(r1); float r2 = r1 - bf2f(h1);
            a01[i] = (short)h0; a11[i] = (short)h1; a21[i] = (short)f2bf(r2);
        }

        __syncthreads();   // previous iteration's frag reads done
        const int abase = ar * 40 + ak;
        *(short8*)&A_s[0][abase] = a00; *(short8*)&A_s[0][abase + 8] = a01;
        *(short8*)&A_s[1][abase] = a10; *(short8*)&A_s[1][abase + 8] = a11;
        *(short8*)&A_s[2][abase] = a20; *(short8*)&A_s[2][abase + 8] = a21;
        __syncthreads();

        short8 af[3][4];
#pragma unroll
        for (int ti = 0; ti < 4; ti++) {
            int off = (wm + ti * 16 + l16) * 40 + quad * 8;
            af[0][ti] = *(const short8*)&A_s[0][off];
            af[1][ti] = *(const short8*)&A_s[1][off];
            af[2][ti] = *(const short8*)&A_s[2][off];
        }
#pragma unroll
        for (int tj = 0; tj < 4; tj++) {
            size_t bbase = (size_t)(n0 + wn + tj * 16 + l16) * 512 + k0 + quad * 8;
            short8 b0 = *(const short8*)(WH + bbase);
            short8 b1 = *(const short8*)(WM + bbase);
            short8 b2 = *(const short8*)(WL + bbase);
#pragma unroll
            for (int ti = 0; ti < 4; ti++) {
                floatx4 c = acc[ti][tj];
                c = __builtin_amdgcn_mfma_f32_16x16x32_bf16(af[0][ti], b0, c, 0, 0, 0);
                c = __builtin_amdgcn_mfma_f32_16x16x32_bf16(af[0][ti], b1, c, 0, 0, 0);
                c = __builtin_amdgcn_mfma_f32_16x16x32_bf16(af[1][ti], b0, c, 0, 0, 0);
                c = __builtin_amdgcn_mfma_f32_16x16x32_bf16(af[0][ti], b2, c, 0, 0, 0);
                c = __builtin_amdgcn_mfma_f32_16x16x32_bf16(af[1][ti], b1, c, 0, 0, 0);
                c = __builtin_amdgcn_mfma_f32_16x16x32_bf16(af[2][ti], b0, c, 0, 0, 0);
                acc[ti][tj] = c;
            }
        }
    }

    // epilogue: D col = lane&15, row = quad*4+reg  (m89-verified layout)
#pragma unroll
    for (int tj = 0; tj < 4; tj++) {
        int n = n0 + wn + tj * 16 + l16;
        float bv = bias[n];
#pragma unroll
        for (int ti = 0; ti < 4; ti++) {
#pragma unroll
            for (int r = 0; r < 4; r++) {
                int pos = wm + ti * 16 + quad * 4 + r;
                bool valid = rs[pos] >= 0;
                float v = valid ? (acc[ti][tj][r] + bv) : 0.f;
                out[((size_t)pos * Bmol + mol) * 512 + n] = v;
            }
        }
    }
}

// ---------------- bonds GEMM via bf16 MFMA: 64 bonds/block, 16 heads, K=512 ----------------
__global__ __launch_bounds__(256) void k_bonds_mfma(
    const float* __restrict__ fB, const float* __restrict__ fBo,
    const short* __restrict__ Wbt, const float* __restrict__ bb_,
    float* __restrict__ bonds, int Nb)
{
    __shared__ short feat[64 * 136];  // [bond][k] pad 136, current BK=128 slice
    __shared__ short wb[16 * 512];    // [h][k] full K, chunk-swizzled by h

    const int tid = threadIdx.x;
    const int j0 = blockIdx.x * 64;

    for (int c = tid; c < 1024; c += 256) {
        int h = c >> 6, cc = c & 63;
        short8 v = *(const short8*)(Wbt + h * 512 + cc * 8);
        *(short8*)&wb[h * 512 + (((cc + h) & 63) * 8)] = v;
    }

    const int wid = tid >> 6, lane = tid & 63;
    const int quad = lane >> 4, l16 = lane & 15;
    floatx4 acc = (floatx4){0.f, 0.f, 0.f, 0.f};

    const int fr = tid >> 2;           // bond row 0..63
    const int fs = (tid & 3) * 32;     // k-seg
    const int j = j0 + fr;

    for (int k0 = 0; k0 < 512; k0 += 128) {
        float x[32];
        if (j < Nb) {
            const float* p = (k0 < 256) ? (fB + (size_t)j * 256 + k0 + fs)
                                        : (fBo + (size_t)j * 256 + (k0 - 256) + fs);
#pragma unroll
            for (int i = 0; i < 8; i++) {
                float4 v = ((const float4*)p)[i];
                x[i * 4 + 0] = v.x; x[i * 4 + 1] = v.y;
                x[i * 4 + 2] = v.z; x[i * 4 + 3] = v.w;
            }
        } else {
#pragma unroll
            for (int i = 0; i < 32; i++) x[i] = 0.f;
        }
        __syncthreads();
#pragma unroll
        for (int c = 0; c < 4; c++) {
            short8 s;
#pragma unroll
            for (int i = 0; i < 8; i++) s[i] = (short)f2bf(x[c * 8 + i]);
            *(short8*)&feat[fr * 136 + fs + c * 8] = s;
        }
        __syncthreads();
#pragma unroll
        for (int kk = 0; kk < 4; kk++) {
            short8 a = *(const short8*)&feat[(wid * 16 + l16) * 136 + kk * 32 + quad * 8];
            int kchunk = (k0 + kk * 32 + quad * 8) >> 3;
            short8 b = *(const short8*)&wb[l16 * 512 + (((kchunk + l16) & 63) * 8)];
            acc = __builtin_amdgcn_mfma_f32_16x16x32_bf16(a, b, acc, 0, 0, 0);
        }
    }
    float bv = bb_[l16];
#pragma unroll
    for (int r = 0; r < 4; r++) {
        int jj = j0 + wid * 16 + quad * 4 + r;
        if (jj < Nb) bonds[(size_t)jj * 16 + l16] = acc[r] + bv;
    }
}

// ---------------- fused scatter + apairs + mask: one block per molecule ----------------
// winner table (128x128 int = 64 KB) lives in LDS; last-update-wins == atomicMax on
// global bond index j (matches .at[idx].set duplicate semantics). Stray bond j=0
// (searchsorted clamp) goes to molecule 0.
__global__ __launch_bounds__(512) void k_pair(
    const int* __restrict__ b2a, const int* __restrict__ b2revb,
    const int* __restrict__ b_scope, const int* __restrict__ a_scope,
    const float* __restrict__ bonds, float* __restrict__ out_ap,
    float* __restrict__ out_mask, int Bmol)
{
    __shared__ int w[16384];
    const int tid = threadIdx.x;
    const int mol = blockIdx.x;

#pragma unroll
    for (int i = 0; i < 8; i++)
        ((int4*)w)[i * 512 + tid] = make_int4(-1, -1, -1, -1);

    const int bs = b_scope[2 * mol];
    const int bc = b_scope[2 * mol + 1];
    const int len = a_scope[2 * mol + 1];
    __syncthreads();

    for (int q = tid; q < bc; q += 512) {
        int j = bs + q;
        int p2 = b2a[j];
        int p1 = b2a[b2revb[j]];
        atomicMax(&w[p1 * 128 + p2], j);
    }
    if (mol == 0 && tid == 0) {
        int p2 = b2a[0];
        int p1 = b2a[b2revb[0]];
        atomicMax(&w[p1 * 128 + p2], 0);
    }
    __syncthreads();

    // mask row (128 floats)
    if (tid < 32) {
        int p = tid * 4;
        float4 mv;
        mv.x = (p + 0 >= len) ? 1.0f : 0.0f;
        mv.y = (p + 1 >= len) ? 1.0f : 0.0f;
        mv.z = (p + 2 >= len) ? 1.0f : 0.0f;
        mv.w = (p + 3 >= len) ? 1.0f : 0.0f;
        *(float4*)&out_mask[mol * 128 + p] = mv;
    }

    const int p1 = tid >> 2;
    float* ob = out_ap + ((size_t)mol * 16 * 128 + p1) * 128;
#pragma unroll
    for (int g = 0; g < 8; g++) {
        int p2q = (tid & 3) + g * 4;           // int4 group index in row p1
        int4 wv = ((const int4*)w)[p1 * 32 + p2q];
        int p2 = p2q * 4;
        bool m0 = (p2 + 0 >= len), m1 = (p2 + 1 >= len);
        bool m2 = (p2 + 2 >= len), m3 = (p2 + 3 >= len);
#pragma unroll
        for (int h = 0; h < 16; h++) {
            float4 v;
            v.x = m0 ? NEG_BIG : (wv.x >= 0 ? bonds[(size_t)wv.x * 16 + h] : 0.f);
            v.y = m1 ? NEG_BIG : (wv.y >= 0 ? bonds[(size_t)wv.y * 16 + h] : 0.f);
            v.z = m2 ? NEG_BIG : (wv.z >= 0 ? bonds[(size_t)wv.z * 16 + h] : 0.f);
            v.w = m3 ? NEG_BIG : (wv.w >= 0 ? bonds[(size_t)wv.w * 16 + h] : 0.f);
            *(float4*)(ob + (size_t)h * 16384 + p2) = v;
        }
    }
}

extern "C" void kernel_launch(void* const* d_in, const int* in_sizes, int n_in,
                              void* d_out, int out_size, void* d_ws, size_t ws_size,
                              hipStream_t stream)
{
    const float* f_atoms     = (const float*)d_in[0];
    const float* f_bonds     = (const float*)d_in[1];
    const float* f_atoms_out = (const float*)d_in[2];
    const float* f_bonds_out = (const float*)d_in[3];
    const int*   b2a         = (const int*)d_in[4];
    const int*   b2revb      = (const int*)d_in[5];
    const int*   a_scope     = (const int*)d_in[6];
    const int*   b_scope     = (const int*)d_in[7];
    const float* W_atom      = (const float*)d_in[9];
    const float* b_atom      = (const float*)d_in[10];
    const float* W_bond      = (const float*)d_in[11];
    const float* b_bond      = (const float*)d_in[12];

    const int Bmol = in_sizes[6] / 2;   // 128
    const int Nb   = in_sizes[4];

    char* ws = (char*)d_ws;
    size_t off = 0;
    float* bonds_ws = (float*)(ws + off); off += ((size_t)Nb * 16 * 4 + 255) & ~(size_t)255;
    short* WH       = (short*)(ws + off); off += 512 * 512 * 2;
    short* WM       = (short*)(ws + off); off += 512 * 512 * 2;
    short* WL       = (short*)(ws + off); off += 512 * 512 * 2;
    short* Wbt      = (short*)(ws + off); off += 16 * 512 * 2;

    float* out_emb  = (float*)d_out;                                // (128, B, 512)
    float* out_ap   = out_emb + (size_t)128 * Bmol * 512;           // (B, 16, 128, 128)
    float* out_mask = out_ap + (size_t)Bmol * 16 * 128 * 128;       // (B, 128)

    hipLaunchKernelGGL(k_prepWa, dim3(1024), dim3(256), 0, stream, W_atom, WH, WM, WL);
    hipLaunchKernelGGL(k_prepWb, dim3(32), dim3(256), 0, stream, W_bond, Wbt);
    hipLaunchKernelGGL(k_atoms_mfma, dim3(4, Bmol), dim3(256), 0, stream,
                       f_atoms, f_atoms_out, a_scope, WH, WM, WL, b_atom, out_emb, Bmol);
    hipLaunchKernelGGL(k_bonds_mfma, dim3((Nb + 63) / 64), dim3(256), 0, stream,
                       f_bonds, f_bonds_out, Wbt, b_bond, bonds_ws, Nb);
    hipLaunchKernelGGL(k_pair, dim3(Bmol), dim3(512), 0, stream,
                       b2a, b2revb, b_scope, a_scope, bonds_ws, out_ap, out_mask, Bmol);
}

// Round 5
// 347.041 us; speedup vs baseline: 1.0353x; 1.0353x over previous
//
#include <hip/hip_runtime.h>
#include <math.h>

#define NEG_BIG (-1e30f)

typedef __attribute__((ext_vector_type(8))) short short8;
typedef __attribute__((ext_vector_type(4))) float floatx4;

__device__ __forceinline__ unsigned short f2bf(float x) {
    unsigned u = __float_as_uint(x);
    unsigned r = (u + 0x7fffu + ((u >> 16) & 1u)) >> 16;
    return (unsigned short)r;
}
__device__ __forceinline__ float bf2f(unsigned short h) {
    return __uint_as_float(((unsigned)h) << 16);
}

// ---------------- prep: split W_atom (512x512, [k][n]) into 3 bf16 planes laid out [n][k] ----------------
__global__ void k_prepWa(const float* __restrict__ W, short* __restrict__ H,
                         short* __restrict__ M, short* __restrict__ L) {
    int t = blockIdx.x * 256 + threadIdx.x;   // 262144
    int n = t >> 9, k = t & 511;
    float x = W[(size_t)k * 512 + n];
    unsigned short h0 = f2bf(x); float r1 = x - bf2f(h0);
    unsigned short h1 = f2bf(r1); float r2 = r1 - bf2f(h1);
    unsigned short h2 = f2bf(r2);
    H[t] = (short)h0; M[t] = (short)h1; L[t] = (short)h2;
}

// ---------------- prep: W_bond (512x16 -> [h][k] bf16) ----------------
__global__ void k_prepWb(const float* __restrict__ Wb, short* __restrict__ Wbt) {
    int t = blockIdx.x * 256 + threadIdx.x;   // 8192
    int h = t >> 9, k = t & 511;
    Wbt[t] = (short)f2bf(Wb[(size_t)k * 16 + h]);
}

// ---------------- atoms GEMM via MFMA, fp32 emulated with 3-way bf16 split (6 products) ----------------
// tile 128x128, BK=32; one block = one molecule (blockIdx.y), 4 n-tiles (blockIdx.x)
// A staged through LDS (needs f32->bf16 split); B fragments loaded DIRECTLY from
// global planes (already [n][k] = MFMA fragment order; 1.5 MB unique -> L2-hot).
__global__ __launch_bounds__(256) void k_atoms_mfma(
    const float* __restrict__ fA, const float* __restrict__ fAo,
    const int* __restrict__ a_scope,
    const short* __restrict__ WH, const short* __restrict__ WM, const short* __restrict__ WL,
    const float* __restrict__ bias, float* __restrict__ out, int Bmol)
{
    __shared__ short A_s[3][128 * 40];   // [split][m][k] pad 40
    __shared__ int rs[128];

    const int tid = threadIdx.x;
    const int n0 = blockIdx.x * 128;
    const int mol = blockIdx.y;

    if (tid < 128) {
        int len = a_scope[2 * mol + 1];
        rs[tid] = (tid < len) ? (a_scope[2 * mol] + tid) : -1;
    }
    const int wid = tid >> 6, lane = tid & 63;
    const int wm = (wid >> 1) * 64, wn = (wid & 1) * 64;
    const int quad = lane >> 4, l16 = lane & 15;

    floatx4 acc[4][4];
#pragma unroll
    for (int i = 0; i < 4; i++)
#pragma unroll
        for (int j = 0; j < 4; j++) acc[i][j] = (floatx4){0.f, 0.f, 0.f, 0.f};

    const int ar = tid >> 1;           // 0..127 : A row in tile
    const int ak = (tid & 1) * 16;     // 0 / 16 : k segment
    __syncthreads();                   // rs ready
    const int asrc = rs[ar];

    for (int k0 = 0; k0 < 512; k0 += 32) {
        // ---- A global load + 3-way bf16 split ----
        float x[16];
        if (asrc >= 0) {
            int kg = k0 + ak;
            const float* p = (kg < 256) ? (fA + (size_t)asrc * 256 + kg)
                                        : (fAo + (size_t)asrc * 256 + (kg - 256));
#pragma unroll
            for (int i = 0; i < 4; i++) {
                float4 v = ((const float4*)p)[i];
                x[i * 4 + 0] = v.x; x[i * 4 + 1] = v.y;
                x[i * 4 + 2] = v.z; x[i * 4 + 3] = v.w;
            }
        } else {
#pragma unroll
            for (int i = 0; i < 16; i++) x[i] = 0.f;
        }
        short8 a00, a01, a10, a11, a20, a21;
#pragma unroll
        for (int i = 0; i < 8; i++) {
            unsigned short h0 = f2bf(x[i]); float r1 = x[i] - bf2f(h0);
            unsigned short h1 = f2bf(r1);   float r2 = r1 - bf2f(h1);
            a00[i] = (short)h0; a10[i] = (short)h1; a20[i] = (short)f2bf(r2);
        }
#pragma unroll
        for (int i = 0; i < 8; i++) {
            float xx = x[8 + i];
            unsigned short h0 = f2bf(xx); float r1 = xx - bf2f(h0);
            unsigned short h1 = f2bf(r1); float r2 = r1 - bf2f(h1);
            a01[i] = (short)h0; a11[i] = (short)h1; a21[i] = (short)f2bf(r2);
        }

        __syncthreads();   // previous iteration's frag reads done
        const int abase = ar * 40 + ak;
        *(short8*)&A_s[0][abase] = a00; *(short8*)&A_s[0][abase + 8] = a01;
        *(short8*)&A_s[1][abase] = a10; *(short8*)&A_s[1][abase + 8] = a11;
        *(short8*)&A_s[2][abase] = a20; *(short8*)&A_s[2][abase + 8] = a21;
        __syncthreads();

        short8 af[3][4];
#pragma unroll
        for (int ti = 0; ti < 4; ti++) {
            int off = (wm + ti * 16 + l16) * 40 + quad * 8;
            af[0][ti] = *(const short8*)&A_s[0][off];
            af[1][ti] = *(const short8*)&A_s[1][off];
            af[2][ti] = *(const short8*)&A_s[2][off];
        }
#pragma unroll
        for (int tj = 0; tj < 4; tj++) {
            size_t bbase = (size_t)(n0 + wn + tj * 16 + l16) * 512 + k0 + quad * 8;
            short8 b0 = *(const short8*)(WH + bbase);
            short8 b1 = *(const short8*)(WM + bbase);
            short8 b2 = *(const short8*)(WL + bbase);
#pragma unroll
            for (int ti = 0; ti < 4; ti++) {
                floatx4 c = acc[ti][tj];
                c = __builtin_amdgcn_mfma_f32_16x16x32_bf16(af[0][ti], b0, c, 0, 0, 0);
                c = __builtin_amdgcn_mfma_f32_16x16x32_bf16(af[0][ti], b1, c, 0, 0, 0);
                c = __builtin_amdgcn_mfma_f32_16x16x32_bf16(af[1][ti], b0, c, 0, 0, 0);
                c = __builtin_amdgcn_mfma_f32_16x16x32_bf16(af[0][ti], b2, c, 0, 0, 0);
                c = __builtin_amdgcn_mfma_f32_16x16x32_bf16(af[1][ti], b1, c, 0, 0, 0);
                c = __builtin_amdgcn_mfma_f32_16x16x32_bf16(af[2][ti], b0, c, 0, 0, 0);
                acc[ti][tj] = c;
            }
        }
    }

    // epilogue: D col = lane&15, row = quad*4+reg  (m89-verified layout)
#pragma unroll
    for (int tj = 0; tj < 4; tj++) {
        int n = n0 + wn + tj * 16 + l16;
        float bv = bias[n];
#pragma unroll
        for (int ti = 0; ti < 4; ti++) {
#pragma unroll
            for (int r = 0; r < 4; r++) {
                int pos = wm + ti * 16 + quad * 4 + r;
                bool valid = rs[pos] >= 0;
                float v = valid ? (acc[ti][tj][r] + bv) : 0.f;
                out[((size_t)pos * Bmol + mol) * 512 + n] = v;
            }
        }
    }
}

// ---------------- bonds GEMM via bf16 MFMA: 64 bonds/block, 16 heads, K=512 ----------------
__global__ __launch_bounds__(256) void k_bonds_mfma(
    const float* __restrict__ fB, const float* __restrict__ fBo,
    const short* __restrict__ Wbt, const float* __restrict__ bb_,
    float* __restrict__ bonds, int Nb)
{
    __shared__ short feat[64 * 136];  // [bond][k] pad 136, current BK=128 slice
    __shared__ short wb[16 * 512];    // [h][k] full K, chunk-swizzled by h

    const int tid = threadIdx.x;
    const int j0 = blockIdx.x * 64;

    for (int c = tid; c < 1024; c += 256) {
        int h = c >> 6, cc = c & 63;
        short8 v = *(const short8*)(Wbt + h * 512 + cc * 8);
        *(short8*)&wb[h * 512 + (((cc + h) & 63) * 8)] = v;
    }

    const int wid = tid >> 6, lane = tid & 63;
    const int quad = lane >> 4, l16 = lane & 15;
    floatx4 acc = (floatx4){0.f, 0.f, 0.f, 0.f};

    const int fr = tid >> 2;           // bond row 0..63
    const int fs = (tid & 3) * 32;     // k-seg
    const int j = j0 + fr;

    for (int k0 = 0; k0 < 512; k0 += 128) {
        float x[32];
        if (j < Nb) {
            const float* p = (k0 < 256) ? (fB + (size_t)j * 256 + k0 + fs)
                                        : (fBo + (size_t)j * 256 + (k0 - 256) + fs);
#pragma unroll
            for (int i = 0; i < 8; i++) {
                float4 v = ((const float4*)p)[i];
                x[i * 4 + 0] = v.x; x[i * 4 + 1] = v.y;
                x[i * 4 + 2] = v.z; x[i * 4 + 3] = v.w;
            }
        } else {
#pragma unroll
            for (int i = 0; i < 32; i++) x[i] = 0.f;
        }
        __syncthreads();
#pragma unroll
        for (int c = 0; c < 4; c++) {
            short8 s;
#pragma unroll
            for (int i = 0; i < 8; i++) s[i] = (short)f2bf(x[c * 8 + i]);
            *(short8*)&feat[fr * 136 + fs + c * 8] = s;
        }
        __syncthreads();
#pragma unroll
        for (int kk = 0; kk < 4; kk++) {
            short8 a = *(const short8*)&feat[(wid * 16 + l16) * 136 + kk * 32 + quad * 8];
            int kchunk = (k0 + kk * 32 + quad * 8) >> 3;
            short8 b = *(const short8*)&wb[l16 * 512 + (((kchunk + l16) & 63) * 8)];
            acc = __builtin_amdgcn_mfma_f32_16x16x32_bf16(a, b, acc, 0, 0, 0);
        }
    }
    float bv = bb_[l16];
#pragma unroll
    for (int r = 0; r < 4; r++) {
        int jj = j0 + wid * 16 + quad * 4 + r;
        if (jj < Nb) bonds[(size_t)jj * 16 + l16] = acc[r] + bv;
    }
}

// ---------------- fused scatter + apairs + mask: 4 blocks per molecule ----------------
// Each block owns a p1-quarter of the 128x128 winner table (32x128 int = 16 KB LDS).
// Collisions for a fixed (p1,p2) all land in one block -> last-update-wins (max j)
// preserved == .at[idx].set duplicate semantics. Stray bond j=0 goes to molecule 0.
__global__ __launch_bounds__(256) void k_pair(
    const int* __restrict__ b2a, const int* __restrict__ b2revb,
    const int* __restrict__ b_scope, const int* __restrict__ a_scope,
    const float* __restrict__ bonds, float* __restrict__ out_ap,
    float* __restrict__ out_mask, int Bmol)
{
    __shared__ int w[32 * 128];
    const int tid = threadIdx.x;
    const int mol = blockIdx.x >> 2;
    const int q   = blockIdx.x & 3;      // p1 quarter

#pragma unroll
    for (int i = 0; i < 4; i++)
        ((int4*)w)[i * 256 + tid] = make_int4(-1, -1, -1, -1);

    const int bs  = b_scope[2 * mol];
    const int bc  = b_scope[2 * mol + 1];
    const int len = a_scope[2 * mol + 1];
    __syncthreads();

    for (int idx = tid; idx < bc; idx += 256) {
        int j = bs + idx;
        int p2 = b2a[j];
        int p1 = b2a[b2revb[j]];
        if ((p1 >> 5) == q) atomicMax(&w[(p1 & 31) * 128 + p2], j);
    }
    if (mol == 0 && tid == 0) {
        int p2 = b2a[0];
        int p1 = b2a[b2revb[0]];
        if ((p1 >> 5) == q) atomicMax(&w[(p1 & 31) * 128 + p2], 0);
    }
    __syncthreads();

    if (q == 0 && tid < 32) {
        int p = tid * 4;
        float4 mv;
        mv.x = (p + 0 >= len) ? 1.0f : 0.0f;
        mv.y = (p + 1 >= len) ? 1.0f : 0.0f;
        mv.z = (p + 2 >= len) ? 1.0f : 0.0f;
        mv.w = (p + 3 >= len) ? 1.0f : 0.0f;
        *(float4*)&out_mask[mol * 128 + p] = mv;
    }

    // write this quarter's 32 p1-rows for all 16 heads
    const int p1l = tid >> 3;            // 0..31 local row
    const int seg = tid & 7;             // 16 floats each
    const int p1g = q * 32 + p1l;
    int4 wv[4];
#pragma unroll
    for (int c = 0; c < 4; c++) wv[c] = ((const int4*)w)[p1l * 32 + seg * 4 + c];
    bool msk[16];
#pragma unroll
    for (int c = 0; c < 16; c++) msk[c] = (seg * 16 + c >= len);

    float* ob = out_ap + ((size_t)mol * 16 * 128 + p1g) * 128 + seg * 16;
#pragma unroll
    for (int h = 0; h < 16; h++) {
        float* op = ob + (size_t)h * 16384;
#pragma unroll
        for (int c = 0; c < 4; c++) {
            const int* wc = (const int*)&wv[c];
            float4 v;
            v.x = msk[c*4+0] ? NEG_BIG : (wc[0] >= 0 ? bonds[(size_t)wc[0] * 16 + h] : 0.f);
            v.y = msk[c*4+1] ? NEG_BIG : (wc[1] >= 0 ? bonds[(size_t)wc[1] * 16 + h] : 0.f);
            v.z = msk[c*4+2] ? NEG_BIG : (wc[2] >= 0 ? bonds[(size_t)wc[2] * 16 + h] : 0.f);
            v.w = msk[c*4+3] ? NEG_BIG : (wc[3] >= 0 ? bonds[(size_t)wc[3] * 16 + h] : 0.f);
            *(float4*)(op + c * 4) = v;
        }
    }
}

extern "C" void kernel_launch(void* const* d_in, const int* in_sizes, int n_in,
                              void* d_out, int out_size, void* d_ws, size_t ws_size,
                              hipStream_t stream)
{
    const float* f_atoms     = (const float*)d_in[0];
    const float* f_bonds     = (const float*)d_in[1];
    const float* f_atoms_out = (const float*)d_in[2];
    const float* f_bonds_out = (const float*)d_in[3];
    const int*   b2a         = (const int*)d_in[4];
    const int*   b2revb      = (const int*)d_in[5];
    const int*   a_scope     = (const int*)d_in[6];
    const int*   b_scope     = (const int*)d_in[7];
    const float* W_atom      = (const float*)d_in[9];
    const float* b_atom      = (const float*)d_in[10];
    const float* W_bond      = (const float*)d_in[11];
    const float* b_bond      = (const float*)d_in[12];

    const int Bmol = in_sizes[6] / 2;   // 128
    const int Nb   = in_sizes[4];

    char* ws = (char*)d_ws;
    size_t off = 0;
    float* bonds_ws = (float*)(ws + off); off += ((size_t)Nb * 16 * 4 + 255) & ~(size_t)255;
    short* WH       = (short*)(ws + off); off += 512 * 512 * 2;
    short* WM       = (short*)(ws + off); off += 512 * 512 * 2;
    short* WL       = (short*)(ws + off); off += 512 * 512 * 2;
    short* Wbt      = (short*)(ws + off); off += 16 * 512 * 2;

    float* out_emb  = (float*)d_out;                                // (128, B, 512)
    float* out_ap   = out_emb + (size_t)128 * Bmol * 512;           // (B, 16, 128, 128)
    float* out_mask = out_ap + (size_t)Bmol * 16 * 128 * 128;       // (B, 128)

    hipLaunchKernelGGL(k_prepWa, dim3(1024), dim3(256), 0, stream, W_atom, WH, WM, WL);
    hipLaunchKernelGGL(k_prepWb, dim3(32), dim3(256), 0, stream, W_bond, Wbt);
    hipLaunchKernelGGL(k_atoms_mfma, dim3(4, Bmol), dim3(256), 0, stream,
                       f_atoms, f_atoms_out, a_scope, WH, WM, WL, b_atom, out_emb, Bmol);
    hipLaunchKernelGGL(k_bonds_mfma, dim3((Nb + 63) / 64), dim3(256), 0, stream,
                       f_bonds, f_bonds_out, Wbt, b_bond, bonds_ws, Nb);
    hipLaunchKernelGGL(k_pair, dim3(Bmol * 4), dim3(256), 0, stream,
                       b2a, b2revb, b_scope, a_scope, bonds_ws, out_ap, out_mask, Bmol);
}

// Round 6
// 343.542 us; speedup vs baseline: 1.0459x; 1.0102x over previous
//
#include <hip/hip_runtime.h>
#include <math.h>

#define NEG_BIG (-1e30f)

typedef __attribute__((ext_vector_type(8))) short short8;
typedef __attribute__((ext_vector_type(4))) float floatx4;

__device__ __forceinline__ unsigned short f2bf(float x) {
    unsigned u = __float_as_uint(x);
    unsigned r = (u + 0x7fffu + ((u >> 16) & 1u)) >> 16;
    return (unsigned short)r;
}
__device__ __forceinline__ float bf2f(unsigned short h) {
    return __uint_as_float(((unsigned)h) << 16);
}

// ---------------- fused prep: W_atom 3-way bf16 split ([n][k] planes) + W_bond [h][k] bf16 ----------------
__global__ void k_prep(const float* __restrict__ W, const float* __restrict__ Wb,
                       short* __restrict__ H, short* __restrict__ M, short* __restrict__ L,
                       short* __restrict__ Wbt) {
    int t = blockIdx.x * 256 + threadIdx.x;
    if (t < 262144) {
        int n = t >> 9, k = t & 511;
        float x = W[(size_t)k * 512 + n];
        unsigned short h0 = f2bf(x); float r1 = x - bf2f(h0);
        unsigned short h1 = f2bf(r1); float r2 = r1 - bf2f(h1);
        unsigned short h2 = f2bf(r2);
        H[t] = (short)h0; M[t] = (short)h1; L[t] = (short)h2;
    } else {
        int u = t - 262144;
        if (u < 8192) {
            int h = u >> 9, k = u & 511;
            Wbt[u] = (short)f2bf(Wb[(size_t)k * 16 + h]);
        }
    }
}

// ---------------- atoms GEMM via MFMA, fp32 emulated with 3-way bf16 split (6 products) ----------------
// tile 128x128, BK=32; one block = one molecule (blockIdx.y), 4 n-tiles (blockIdx.x)
// A double-buffered in LDS (single barrier per K-iter); B fragments loaded DIRECTLY
// from global planes (already [n][k] = MFMA fragment order; 1.5 MB unique -> L2-hot).
__global__ __launch_bounds__(256) void k_atoms_mfma(
    const float* __restrict__ fA, const float* __restrict__ fAo,
    const int* __restrict__ a_scope,
    const short* __restrict__ WH, const short* __restrict__ WM, const short* __restrict__ WL,
    const float* __restrict__ bias, float* __restrict__ out, int Bmol)
{
    __shared__ short A_s[2][3][128 * 40];   // [buf][split][m][k] pad 40
    __shared__ int rs[128];

    const int tid = threadIdx.x;
    const int n0 = blockIdx.x * 128;
    const int mol = blockIdx.y;

    if (tid < 128) {
        int len = a_scope[2 * mol + 1];
        rs[tid] = (tid < len) ? (a_scope[2 * mol] + tid) : -1;
    }
    const int wid = tid >> 6, lane = tid & 63;
    const int wm = (wid >> 1) * 64, wn = (wid & 1) * 64;
    const int quad = lane >> 4, l16 = lane & 15;

    floatx4 acc[4][4];
#pragma unroll
    for (int i = 0; i < 4; i++)
#pragma unroll
        for (int j = 0; j < 4; j++) acc[i][j] = (floatx4){0.f, 0.f, 0.f, 0.f};

    const int ar = tid >> 1;           // 0..127 : A row in tile
    const int ak = (tid & 1) * 16;     // 0 / 16 : k segment
    __syncthreads();                   // rs ready
    const int asrc = rs[ar];

    int buf = 0;
    for (int k0 = 0; k0 < 512; k0 += 32, buf ^= 1) {
        // ---- A global load + 3-way bf16 split ----
        float x[16];
        if (asrc >= 0) {
            int kg = k0 + ak;
            const float* p = (kg < 256) ? (fA + (size_t)asrc * 256 + kg)
                                        : (fAo + (size_t)asrc * 256 + (kg - 256));
#pragma unroll
            for (int i = 0; i < 4; i++) {
                float4 v = ((const float4*)p)[i];
                x[i * 4 + 0] = v.x; x[i * 4 + 1] = v.y;
                x[i * 4 + 2] = v.z; x[i * 4 + 3] = v.w;
            }
        } else {
#pragma unroll
            for (int i = 0; i < 16; i++) x[i] = 0.f;
        }
        short8 a00, a01, a10, a11, a20, a21;
#pragma unroll
        for (int i = 0; i < 8; i++) {
            unsigned short h0 = f2bf(x[i]); float r1 = x[i] - bf2f(h0);
            unsigned short h1 = f2bf(r1);   float r2 = r1 - bf2f(h1);
            a00[i] = (short)h0; a10[i] = (short)h1; a20[i] = (short)f2bf(r2);
        }
#pragma unroll
        for (int i = 0; i < 8; i++) {
            float xx = x[8 + i];
            unsigned short h0 = f2bf(xx); float r1 = xx - bf2f(h0);
            unsigned short h1 = f2bf(r1); float r2 = r1 - bf2f(h1);
            a01[i] = (short)h0; a11[i] = (short)h1; a21[i] = (short)f2bf(r2);
        }

        // write current buffer (safe: all waves finished reading this buffer
        // two iters ago before they could pass the previous barrier)
        const int abase = ar * 40 + ak;
        *(short8*)&A_s[buf][0][abase] = a00; *(short8*)&A_s[buf][0][abase + 8] = a01;
        *(short8*)&A_s[buf][1][abase] = a10; *(short8*)&A_s[buf][1][abase + 8] = a11;
        *(short8*)&A_s[buf][2][abase] = a20; *(short8*)&A_s[buf][2][abase + 8] = a21;
        __syncthreads();   // single barrier per iter

        short8 af[3][4];
#pragma unroll
        for (int ti = 0; ti < 4; ti++) {
            int off = (wm + ti * 16 + l16) * 40 + quad * 8;
            af[0][ti] = *(const short8*)&A_s[buf][0][off];
            af[1][ti] = *(const short8*)&A_s[buf][1][off];
            af[2][ti] = *(const short8*)&A_s[buf][2][off];
        }
#pragma unroll
        for (int tj = 0; tj < 4; tj++) {
            size_t bbase = (size_t)(n0 + wn + tj * 16 + l16) * 512 + k0 + quad * 8;
            short8 b0 = *(const short8*)(WH + bbase);
            short8 b1 = *(const short8*)(WM + bbase);
            short8 b2 = *(const short8*)(WL + bbase);
#pragma unroll
            for (int ti = 0; ti < 4; ti++) {
                floatx4 c = acc[ti][tj];
                c = __builtin_amdgcn_mfma_f32_16x16x32_bf16(af[0][ti], b0, c, 0, 0, 0);
                c = __builtin_amdgcn_mfma_f32_16x16x32_bf16(af[0][ti], b1, c, 0, 0, 0);
                c = __builtin_amdgcn_mfma_f32_16x16x32_bf16(af[1][ti], b0, c, 0, 0, 0);
                c = __builtin_amdgcn_mfma_f32_16x16x32_bf16(af[0][ti], b2, c, 0, 0, 0);
                c = __builtin_amdgcn_mfma_f32_16x16x32_bf16(af[1][ti], b1, c, 0, 0, 0);
                c = __builtin_amdgcn_mfma_f32_16x16x32_bf16(af[2][ti], b0, c, 0, 0, 0);
                acc[ti][tj] = c;
            }
        }
    }

    // epilogue: D col = lane&15, row = quad*4+reg  (m89-verified layout)
#pragma unroll
    for (int tj = 0; tj < 4; tj++) {
        int n = n0 + wn + tj * 16 + l16;
        float bv = bias[n];
#pragma unroll
        for (int ti = 0; ti < 4; ti++) {
#pragma unroll
            for (int r = 0; r < 4; r++) {
                int pos = wm + ti * 16 + quad * 4 + r;
                bool valid = rs[pos] >= 0;
                float v = valid ? (acc[ti][tj][r] + bv) : 0.f;
                out[((size_t)pos * Bmol + mol) * 512 + n] = v;
            }
        }
    }
}

// ---------------- bonds GEMM via bf16 MFMA: 64 bonds/block, 16 heads, K=512 ----------------
__global__ __launch_bounds__(256) void k_bonds_mfma(
    const float* __restrict__ fB, const float* __restrict__ fBo,
    const short* __restrict__ Wbt, const float* __restrict__ bb_,
    float* __restrict__ bonds, int Nb)
{
    __shared__ short feat[64 * 136];  // [bond][k] pad 136, current BK=128 slice
    __shared__ short wb[16 * 512];    // [h][k] full K, chunk-swizzled by h

    const int tid = threadIdx.x;
    const int j0 = blockIdx.x * 64;

    for (int c = tid; c < 1024; c += 256) {
        int h = c >> 6, cc = c & 63;
        short8 v = *(const short8*)(Wbt + h * 512 + cc * 8);
        *(short8*)&wb[h * 512 + (((cc + h) & 63) * 8)] = v;
    }

    const int wid = tid >> 6, lane = tid & 63;
    const int quad = lane >> 4, l16 = lane & 15;
    floatx4 acc = (floatx4){0.f, 0.f, 0.f, 0.f};

    const int fr = tid >> 2;           // bond row 0..63
    const int fs = (tid & 3) * 32;     // k-seg
    const int j = j0 + fr;

    for (int k0 = 0; k0 < 512; k0 += 128) {
        float x[32];
        if (j < Nb) {
            const float* p = (k0 < 256) ? (fB + (size_t)j * 256 + k0 + fs)
                                        : (fBo + (size_t)j * 256 + (k0 - 256) + fs);
#pragma unroll
            for (int i = 0; i < 8; i++) {
                float4 v = ((const float4*)p)[i];
                x[i * 4 + 0] = v.x; x[i * 4 + 1] = v.y;
                x[i * 4 + 2] = v.z; x[i * 4 + 3] = v.w;
            }
        } else {
#pragma unroll
            for (int i = 0; i < 32; i++) x[i] = 0.f;
        }
        __syncthreads();
#pragma unroll
        for (int c = 0; c < 4; c++) {
            short8 s;
#pragma unroll
            for (int i = 0; i < 8; i++) s[i] = (short)f2bf(x[c * 8 + i]);
            *(short8*)&feat[fr * 136 + fs + c * 8] = s;
        }
        __syncthreads();
#pragma unroll
        for (int kk = 0; kk < 4; kk++) {
            short8 a = *(const short8*)&feat[(wid * 16 + l16) * 136 + kk * 32 + quad * 8];
            int kchunk = (k0 + kk * 32 + quad * 8) >> 3;
            short8 b = *(const short8*)&wb[l16 * 512 + (((kchunk + l16) & 63) * 8)];
            acc = __builtin_amdgcn_mfma_f32_16x16x32_bf16(a, b, acc, 0, 0, 0);
        }
    }
    float bv = bb_[l16];
#pragma unroll
    for (int r = 0; r < 4; r++) {
        int jj = j0 + wid * 16 + quad * 4 + r;
        if (jj < Nb) bonds[(size_t)jj * 16 + l16] = acc[r] + bv;
    }
}

// ---------------- fused scatter + apairs + mask: 4 blocks per molecule ----------------
// Each block owns a p1-quarter of the 128x128 winner table (32x128 int = 16 KB LDS).
// Collisions for a fixed (p1,p2) all land in one block -> last-update-wins (max j)
// preserved == .at[idx].set duplicate semantics. Stray bond j=0 goes to molecule 0.
__global__ __launch_bounds__(256) void k_pair(
    const int* __restrict__ b2a, const int* __restrict__ b2revb,
    const int* __restrict__ b_scope, const int* __restrict__ a_scope,
    const float* __restrict__ bonds, float* __restrict__ out_ap,
    float* __restrict__ out_mask, int Bmol)
{
    __shared__ int w[32 * 128];
    const int tid = threadIdx.x;
    const int mol = blockIdx.x >> 2;
    const int q   = blockIdx.x & 3;      // p1 quarter

#pragma unroll
    for (int i = 0; i < 4; i++)
        ((int4*)w)[i * 256 + tid] = make_int4(-1, -1, -1, -1);

    const int bs  = b_scope[2 * mol];
    const int bc  = b_scope[2 * mol + 1];
    const int len = a_scope[2 * mol + 1];
    __syncthreads();

    for (int idx = tid; idx < bc; idx += 256) {
        int j = bs + idx;
        int p2 = b2a[j];
        int p1 = b2a[b2revb[j]];
        if ((p1 >> 5) == q) atomicMax(&w[(p1 & 31) * 128 + p2], j);
    }
    if (mol == 0 && tid == 0) {
        int p2 = b2a[0];
        int p1 = b2a[b2revb[0]];
        if ((p1 >> 5) == q) atomicMax(&w[(p1 & 31) * 128 + p2], 0);
    }
    __syncthreads();

    if (q == 0 && tid < 32) {
        int p = tid * 4;
        float4 mv;
        mv.x = (p + 0 >= len) ? 1.0f : 0.0f;
        mv.y = (p + 1 >= len) ? 1.0f : 0.0f;
        mv.z = (p + 2 >= len) ? 1.0f : 0.0f;
        mv.w = (p + 3 >= len) ? 1.0f : 0.0f;
        *(float4*)&out_mask[mol * 128 + p] = mv;
    }

    // write this quarter's 32 p1-rows for all 16 heads
    const int p1l = tid >> 3;            // 0..31 local row
    const int seg = tid & 7;             // 16 floats each
    const int p1g = q * 32 + p1l;
    int4 wv[4];
#pragma unroll
    for (int c = 0; c < 4; c++) wv[c] = ((const int4*)w)[p1l * 32 + seg * 4 + c];
    bool msk[16];
#pragma unroll
    for (int c = 0; c < 16; c++) msk[c] = (seg * 16 + c >= len);

    float* ob = out_ap + ((size_t)mol * 16 * 128 + p1g) * 128 + seg * 16;
#pragma unroll
    for (int h = 0; h < 16; h++) {
        float* op = ob + (size_t)h * 16384;
#pragma unroll
        for (int c = 0; c < 4; c++) {
            const int* wc = (const int*)&wv[c];
            float4 v;
            v.x = msk[c*4+0] ? NEG_BIG : (wc[0] >= 0 ? bonds[(size_t)wc[0] * 16 + h] : 0.f);
            v.y = msk[c*4+1] ? NEG_BIG : (wc[1] >= 0 ? bonds[(size_t)wc[1] * 16 + h] : 0.f);
            v.z = msk[c*4+2] ? NEG_BIG : (wc[2] >= 0 ? bonds[(size_t)wc[2] * 16 + h] : 0.f);
            v.w = msk[c*4+3] ? NEG_BIG : (wc[3] >= 0 ? bonds[(size_t)wc[3] * 16 + h] : 0.f);
            *(float4*)(op + c * 4) = v;
        }
    }
}

extern "C" void kernel_launch(void* const* d_in, const int* in_sizes, int n_in,
                              void* d_out, int out_size, void* d_ws, size_t ws_size,
                              hipStream_t stream)
{
    const float* f_atoms     = (const float*)d_in[0];
    const float* f_bonds     = (const float*)d_in[1];
    const float* f_atoms_out = (const float*)d_in[2];
    const float* f_bonds_out = (const float*)d_in[3];
    const int*   b2a         = (const int*)d_in[4];
    const int*   b2revb      = (const int*)d_in[5];
    const int*   a_scope     = (const int*)d_in[6];
    const int*   b_scope     = (const int*)d_in[7];
    const float* W_atom      = (const float*)d_in[9];
    const float* b_atom      = (const float*)d_in[10];
    const float* W_bond      = (const float*)d_in[11];
    const float* b_bond      = (const float*)d_in[12];

    const int Bmol = in_sizes[6] / 2;   // 128
    const int Nb   = in_sizes[4];

    char* ws = (char*)d_ws;
    size_t off = 0;
    float* bonds_ws = (float*)(ws + off); off += ((size_t)Nb * 16 * 4 + 255) & ~(size_t)255;
    short* WH       = (short*)(ws + off); off += 512 * 512 * 2;
    short* WM       = (short*)(ws + off); off += 512 * 512 * 2;
    short* WL       = (short*)(ws + off); off += 512 * 512 * 2;
    short* Wbt      = (short*)(ws + off); off += 16 * 512 * 2;

    float* out_emb  = (float*)d_out;                                // (128, B, 512)
    float* out_ap   = out_emb + (size_t)128 * Bmol * 512;           // (B, 16, 128, 128)
    float* out_mask = out_ap + (size_t)Bmol * 16 * 128 * 128;       // (B, 128)

    hipLaunchKernelGGL(k_prep, dim3(1056), dim3(256), 0, stream,
                       W_atom, W_bond, WH, WM, WL, Wbt);
    hipLaunchKernelGGL(k_atoms_mfma, dim3(4, Bmol), dim3(256), 0, stream,
                       f_atoms, f_atoms_out, a_scope, WH, WM, WL, b_atom, out_emb, Bmol);
    hipLaunchKernelGGL(k_bonds_mfma, dim3((Nb + 63) / 64), dim3(256), 0, stream,
                       f_bonds, f_bonds_out, Wbt, b_bond, bonds_ws, Nb);
    hipLaunchKernelGGL(k_pair, dim3(Bmol * 4), dim3(256), 0, stream,
                       b2a, b2revb, b_scope, a_scope, bonds_ws, out_ap, out_mask, Bmol);
}

// Round 7
// 333.783 us; speedup vs baseline: 1.0764x; 1.0292x over previous
//
#include <hip/hip_runtime.h>
#include <math.h>

#define NEG_BIG (-1e30f)

typedef __attribute__((ext_vector_type(8))) short short8;
typedef __attribute__((ext_vector_type(4))) float floatx4;

__device__ __forceinline__ unsigned short f2bf(float x) {
    unsigned u = __float_as_uint(x);
    unsigned r = (u + 0x7fffu + ((u >> 16) & 1u)) >> 16;
    return (unsigned short)r;
}
__device__ __forceinline__ float bf2f(unsigned short h) {
    return __uint_as_float(((unsigned)h) << 16);
}

// ---------------- fused prep: W_atom 3-way bf16 split ([n][k] planes) + W_bond [h][k] bf16 ----------------
__global__ void k_prep(const float* __restrict__ W, const float* __restrict__ Wb,
                       short* __restrict__ H, short* __restrict__ M, short* __restrict__ L,
                       short* __restrict__ Wbt) {
    int t = blockIdx.x * 256 + threadIdx.x;
    if (t < 262144) {
        int n = t >> 9, k = t & 511;
        float x = W[(size_t)k * 512 + n];
        unsigned short h0 = f2bf(x); float r1 = x - bf2f(h0);
        unsigned short h1 = f2bf(r1); float r2 = r1 - bf2f(h1);
        unsigned short h2 = f2bf(r2);
        H[t] = (short)h0; M[t] = (short)h1; L[t] = (short)h2;
    } else {
        int u = t - 262144;
        if (u < 8192) {
            int h = u >> 9, k = u & 511;
            Wbt[u] = (short)f2bf(Wb[(size_t)k * 16 + h]);
        }
    }
}

// ---------------- atoms GEMM via MFMA, fp32 emulated with 3-way bf16 split (6 products) ----------------
// tile 128x128, BK=32; one block = one molecule (blockIdx.y), 4 n-tiles (blockIdx.x)
// A double-buffered in LDS (single barrier per K-iter); B fragments loaded DIRECTLY
// from global planes (already [n][k] = MFMA fragment order; 1.5 MB unique -> L2-hot).
__global__ __launch_bounds__(256) void k_atoms_mfma(
    const float* __restrict__ fA, const float* __restrict__ fAo,
    const int* __restrict__ a_scope,
    const short* __restrict__ WH, const short* __restrict__ WM, const short* __restrict__ WL,
    const float* __restrict__ bias, float* __restrict__ out, int Bmol)
{
    __shared__ short A_s[2][3][128 * 40];   // [buf][split][m][k] pad 40
    __shared__ int rs[128];

    const int tid = threadIdx.x;
    const int n0 = blockIdx.x * 128;
    const int mol = blockIdx.y;

    if (tid < 128) {
        int len = a_scope[2 * mol + 1];
        rs[tid] = (tid < len) ? (a_scope[2 * mol] + tid) : -1;
    }
    const int wid = tid >> 6, lane = tid & 63;
    const int wm = (wid >> 1) * 64, wn = (wid & 1) * 64;
    const int quad = lane >> 4, l16 = lane & 15;

    floatx4 acc[4][4];
#pragma unroll
    for (int i = 0; i < 4; i++)
#pragma unroll
        for (int j = 0; j < 4; j++) acc[i][j] = (floatx4){0.f, 0.f, 0.f, 0.f};

    const int ar = tid >> 1;           // 0..127 : A row in tile
    const int ak = (tid & 1) * 16;     // 0 / 16 : k segment
    __syncthreads();                   // rs ready
    const int asrc = rs[ar];

    int buf = 0;
    for (int k0 = 0; k0 < 512; k0 += 32, buf ^= 1) {
        // ---- A global load + 3-way bf16 split ----
        float x[16];
        if (asrc >= 0) {
            int kg = k0 + ak;
            const float* p = (kg < 256) ? (fA + (size_t)asrc * 256 + kg)
                                        : (fAo + (size_t)asrc * 256 + (kg - 256));
#pragma unroll
            for (int i = 0; i < 4; i++) {
                float4 v = ((const float4*)p)[i];
                x[i * 4 + 0] = v.x; x[i * 4 + 1] = v.y;
                x[i * 4 + 2] = v.z; x[i * 4 + 3] = v.w;
            }
        } else {
#pragma unroll
            for (int i = 0; i < 16; i++) x[i] = 0.f;
        }
        short8 a00, a01, a10, a11, a20, a21;
#pragma unroll
        for (int i = 0; i < 8; i++) {
            unsigned short h0 = f2bf(x[i]); float r1 = x[i] - bf2f(h0);
            unsigned short h1 = f2bf(r1);   float r2 = r1 - bf2f(h1);
            a00[i] = (short)h0; a10[i] = (short)h1; a20[i] = (short)f2bf(r2);
        }
#pragma unroll
        for (int i = 0; i < 8; i++) {
            float xx = x[8 + i];
            unsigned short h0 = f2bf(xx); float r1 = xx - bf2f(h0);
            unsigned short h1 = f2bf(r1); float r2 = r1 - bf2f(h1);
            a01[i] = (short)h0; a11[i] = (short)h1; a21[i] = (short)f2bf(r2);
        }

        const int abase = ar * 40 + ak;
        *(short8*)&A_s[buf][0][abase] = a00; *(short8*)&A_s[buf][0][abase + 8] = a01;
        *(short8*)&A_s[buf][1][abase] = a10; *(short8*)&A_s[buf][1][abase + 8] = a11;
        *(short8*)&A_s[buf][2][abase] = a20; *(short8*)&A_s[buf][2][abase + 8] = a21;
        __syncthreads();   // single barrier per iter

        short8 af[3][4];
#pragma unroll
        for (int ti = 0; ti < 4; ti++) {
            int off = (wm + ti * 16 + l16) * 40 + quad * 8;
            af[0][ti] = *(const short8*)&A_s[buf][0][off];
            af[1][ti] = *(const short8*)&A_s[buf][1][off];
            af[2][ti] = *(const short8*)&A_s[buf][2][off];
        }
#pragma unroll
        for (int tj = 0; tj < 4; tj++) {
            size_t bbase = (size_t)(n0 + wn + tj * 16 + l16) * 512 + k0 + quad * 8;
            short8 b0 = *(const short8*)(WH + bbase);
            short8 b1 = *(const short8*)(WM + bbase);
            short8 b2 = *(const short8*)(WL + bbase);
#pragma unroll
            for (int ti = 0; ti < 4; ti++) {
                floatx4 c = acc[ti][tj];
                c = __builtin_amdgcn_mfma_f32_16x16x32_bf16(af[0][ti], b0, c, 0, 0, 0);
                c = __builtin_amdgcn_mfma_f32_16x16x32_bf16(af[0][ti], b1, c, 0, 0, 0);
                c = __builtin_amdgcn_mfma_f32_16x16x32_bf16(af[1][ti], b0, c, 0, 0, 0);
                c = __builtin_amdgcn_mfma_f32_16x16x32_bf16(af[0][ti], b2, c, 0, 0, 0);
                c = __builtin_amdgcn_mfma_f32_16x16x32_bf16(af[1][ti], b1, c, 0, 0, 0);
                c = __builtin_amdgcn_mfma_f32_16x16x32_bf16(af[2][ti], b0, c, 0, 0, 0);
                acc[ti][tj] = c;
            }
        }
    }

    // epilogue: D col = lane&15, row = quad*4+reg  (m89-verified layout)
#pragma unroll
    for (int tj = 0; tj < 4; tj++) {
        int n = n0 + wn + tj * 16 + l16;
        float bv = bias[n];
#pragma unroll
        for (int ti = 0; ti < 4; ti++) {
#pragma unroll
            for (int r = 0; r < 4; r++) {
                int pos = wm + ti * 16 + quad * 4 + r;
                bool valid = rs[pos] >= 0;
                float v = valid ? (acc[ti][tj][r] + bv) : 0.f;
                out[((size_t)pos * Bmol + mol) * 512 + n] = v;
            }
        }
    }
}

// ---------------- bonds GEMM via bf16 MFMA: 64 bonds/block, 16 heads, K=512 ----------------
__global__ __launch_bounds__(256) void k_bonds_mfma(
    const float* __restrict__ fB, const float* __restrict__ fBo,
    const short* __restrict__ Wbt, const float* __restrict__ bb_,
    float* __restrict__ bonds, int Nb)
{
    __shared__ short feat[64 * 136];  // [bond][k] pad 136, current BK=128 slice
    __shared__ short wb[16 * 512];    // [h][k] full K, chunk-swizzled by h

    const int tid = threadIdx.x;
    const int j0 = blockIdx.x * 64;

    for (int c = tid; c < 1024; c += 256) {
        int h = c >> 6, cc = c & 63;
        short8 v = *(const short8*)(Wbt + h * 512 + cc * 8);
        *(short8*)&wb[h * 512 + (((cc + h) & 63) * 8)] = v;
    }

    const int wid = tid >> 6, lane = tid & 63;
    const int quad = lane >> 4, l16 = lane & 15;
    floatx4 acc = (floatx4){0.f, 0.f, 0.f, 0.f};

    const int fr = tid >> 2;           // bond row 0..63
    const int fs = (tid & 3) * 32;     // k-seg
    const int j = j0 + fr;

    for (int k0 = 0; k0 < 512; k0 += 128) {
        float x[32];
        if (j < Nb) {
            const float* p = (k0 < 256) ? (fB + (size_t)j * 256 + k0 + fs)
                                        : (fBo + (size_t)j * 256 + (k0 - 256) + fs);
#pragma unroll
            for (int i = 0; i < 8; i++) {
                float4 v = ((const float4*)p)[i];
                x[i * 4 + 0] = v.x; x[i * 4 + 1] = v.y;
                x[i * 4 + 2] = v.z; x[i * 4 + 3] = v.w;
            }
        } else {
#pragma unroll
            for (int i = 0; i < 32; i++) x[i] = 0.f;
        }
        __syncthreads();
#pragma unroll
        for (int c = 0; c < 4; c++) {
            short8 s;
#pragma unroll
            for (int i = 0; i < 8; i++) s[i] = (short)f2bf(x[c * 8 + i]);
            *(short8*)&feat[fr * 136 + fs + c * 8] = s;
        }
        __syncthreads();
#pragma unroll
        for (int kk = 0; kk < 4; kk++) {
            short8 a = *(const short8*)&feat[(wid * 16 + l16) * 136 + kk * 32 + quad * 8];
            int kchunk = (k0 + kk * 32 + quad * 8) >> 3;
            short8 b = *(const short8*)&wb[l16 * 512 + (((kchunk + l16) & 63) * 8)];
            acc = __builtin_amdgcn_mfma_f32_16x16x32_bf16(a, b, acc, 0, 0, 0);
        }
    }
    float bv = bb_[l16];
#pragma unroll
    for (int r = 0; r < 4; r++) {
        int jj = j0 + wid * 16 + quad * 4 + r;
        if (jj < Nb) bonds[(size_t)jj * 16 + l16] = acc[r] + bv;
    }
}

// ---------------- fused scatter + apairs + mask: 4 blocks per molecule ----------------
// Block owns a p1-quarter of the winner table (32x128 int = 16 KB LDS). This
// molecule's bond rows (bc+1 <= 257 rows x 16 heads) are staged in LDS (stride 17
// breaks the 16-float power-of-2 bank aliasing); slot 257 is a zero row serving
// w<0 cells. Last-update-wins (max j) == .at[idx].set duplicate semantics; stray
// bond j=0 goes to molecule 0 (jbase = bs-1 = 0 stages row 0 there).
__global__ __launch_bounds__(256) void k_pair(
    const int* __restrict__ b2a, const int* __restrict__ b2revb,
    const int* __restrict__ b_scope, const int* __restrict__ a_scope,
    const float* __restrict__ bonds, float* __restrict__ out_ap,
    float* __restrict__ out_mask, int Bmol)
{
    __shared__ int w[32 * 128];        // 16 KB
    __shared__ float bS[258 * 17];     // 17.5 KB
    const int tid = threadIdx.x;
    const int mol = blockIdx.x >> 2;
    const int q   = blockIdx.x & 3;    // p1 quarter

#pragma unroll
    for (int i = 0; i < 4; i++)
        ((int4*)w)[i * 256 + tid] = make_int4(-1, -1, -1, -1);
    if (tid < 17) bS[257 * 17 + tid] = 0.f;   // zero row for w<0

    const int bs  = b_scope[2 * mol];
    const int bc  = b_scope[2 * mol + 1];
    const int len = a_scope[2 * mol + 1];
    const int jbase = bs - 1;
    __syncthreads();

    // scatter into winner quarter
    for (int idx = tid; idx < bc; idx += 256) {
        int j = bs + idx;
        int p2 = b2a[j];
        int p1 = b2a[b2revb[j]];
        if ((p1 >> 5) == q) atomicMax(&w[(p1 & 31) * 128 + p2], j);
    }
    if (mol == 0 && tid == 0) {
        int p2 = b2a[0];
        int p1 = b2a[b2revb[0]];
        if ((p1 >> 5) == q) atomicMax(&w[(p1 & 31) * 128 + p2], 0);
    }

    // stage bond rows jbase .. jbase+bc  (R = bc+1 rows, 16 floats each)
    const int R4 = (bc + 1) * 4;
    for (int i2 = tid; i2 < R4; i2 += 256) {
        int r = i2 >> 2, c = i2 & 3;
        float4 v = *(const float4*)&bonds[((size_t)(jbase + r)) * 16 + c * 4];
        float* d = &bS[r * 17 + c * 4];
        d[0] = v.x; d[1] = v.y; d[2] = v.z; d[3] = v.w;
    }
    __syncthreads();

    if (q == 0 && tid < 32) {
        int p = tid * 4;
        float4 mv;
        mv.x = (p + 0 >= len) ? 1.0f : 0.0f;
        mv.y = (p + 1 >= len) ? 1.0f : 0.0f;
        mv.z = (p + 2 >= len) ? 1.0f : 0.0f;
        mv.w = (p + 3 >= len) ? 1.0f : 0.0f;
        *(float4*)&out_mask[mol * 128 + p] = mv;
    }

    // write this quarter's 32 p1-rows for all 16 heads
    const int p1l = tid >> 3;            // 0..31 local row
    const int seg = tid & 7;             // 16 floats each
    const int p1g = q * 32 + p1l;
    int4 wv[4];
#pragma unroll
    for (int c = 0; c < 4; c++) wv[c] = ((const int4*)w)[p1l * 32 + seg * 4 + c];
    int eidx[16];
#pragma unroll
    for (int c = 0; c < 4; c++) {
        const int* wc = (const int*)&wv[c];
#pragma unroll
        for (int k = 0; k < 4; k++) {
            int ww = wc[k];
            eidx[c * 4 + k] = (ww >= 0) ? (ww - jbase) * 17 : 257 * 17;
        }
    }
    bool msk[16];
#pragma unroll
    for (int c = 0; c < 16; c++) msk[c] = (seg * 16 + c >= len);

    float* ob = out_ap + ((size_t)mol * 16 * 128 + p1g) * 128 + seg * 16;
#pragma unroll
    for (int h = 0; h < 16; h++) {
        float* op = ob + (size_t)h * 16384;
#pragma unroll
        for (int c = 0; c < 4; c++) {
            float4 v;
            v.x = msk[c*4+0] ? NEG_BIG : bS[eidx[c*4+0] + h];
            v.y = msk[c*4+1] ? NEG_BIG : bS[eidx[c*4+1] + h];
            v.z = msk[c*4+2] ? NEG_BIG : bS[eidx[c*4+2] + h];
            v.w = msk[c*4+3] ? NEG_BIG : bS[eidx[c*4+3] + h];
            *(float4*)(op + c * 4) = v;
        }
    }
}

extern "C" void kernel_launch(void* const* d_in, const int* in_sizes, int n_in,
                              void* d_out, int out_size, void* d_ws, size_t ws_size,
                              hipStream_t stream)
{
    const float* f_atoms     = (const float*)d_in[0];
    const float* f_bonds     = (const float*)d_in[1];
    const float* f_atoms_out = (const float*)d_in[2];
    const float* f_bonds_out = (const float*)d_in[3];
    const int*   b2a         = (const int*)d_in[4];
    const int*   b2revb      = (const int*)d_in[5];
    const int*   a_scope     = (const int*)d_in[6];
    const int*   b_scope     = (const int*)d_in[7];
    const float* W_atom      = (const float*)d_in[9];
    const float* b_atom      = (const float*)d_in[10];
    const float* W_bond      = (const float*)d_in[11];
    const float* b_bond      = (const float*)d_in[12];

    const int Bmol = in_sizes[6] / 2;   // 128
    const int Nb   = in_sizes[4];

    char* ws = (char*)d_ws;
    size_t off = 0;
    float* bonds_ws = (float*)(ws + off); off += ((size_t)Nb * 16 * 4 + 255) & ~(size_t)255;
    short* WH       = (short*)(ws + off); off += 512 * 512 * 2;
    short* WM       = (short*)(ws + off); off += 512 * 512 * 2;
    short* WL       = (short*)(ws + off); off += 512 * 512 * 2;
    short* Wbt      = (short*)(ws + off); off += 16 * 512 * 2;

    float* out_emb  = (float*)d_out;                                // (128, B, 512)
    float* out_ap   = out_emb + (size_t)128 * Bmol * 512;           // (B, 16, 128, 128)
    float* out_mask = out_ap + (size_t)Bmol * 16 * 128 * 128;       // (B, 128)

    hipLaunchKernelGGL(k_prep, dim3(1056), dim3(256), 0, stream,
                       W_atom, W_bond, WH, WM, WL, Wbt);
    hipLaunchKernelGGL(k_atoms_mfma, dim3(4, Bmol), dim3(256), 0, stream,
                       f_atoms, f_atoms_out, a_scope, WH, WM, WL, b_atom, out_emb, Bmol);
    hipLaunchKernelGGL(k_bonds_mfma, dim3((Nb + 63) / 64), dim3(256), 0, stream,
                       f_bonds, f_bonds_out, Wbt, b_bond, bonds_ws, Nb);
    hipLaunchKernelGGL(k_pair, dim3(Bmol * 4), dim3(256), 0, stream,
                       b2a, b2revb, b_scope, a_scope, bonds_ws, out_ap, out_mask, Bmol);
}